// Round 1
// baseline (81.490 us; speedup 1.0000x reference)
//
#include <hip/hip_runtime.h>
#include <math.h>

#define BB 64
#define TT 2000
#define DD 512
#define HH 256
#define KK 5
#define PP (3*KK)       // 15
#define TCHUNKS 16
#define TCHUNK (TT/TCHUNKS)   // 125
#define D4 (DD/4)       // 128

// ws layout (floats):
//   [0, BB*TT)                         align
//   [BB*TT, BB*TT + BB*TCHUNKS*DD)     partials
// total = 128000 + 524288 floats ≈ 2.6 MB

// ---------------------------------------------------------------------------
// Kernel 1: per-batch MLP + align.  weights = softmax over singleton axis = 1.
// ---------------------------------------------------------------------------
__global__ __launch_bounds__(256) void mlp_align_kernel(
    const float* __restrict__ state,   // (B,1,D)
    const float* __restrict__ W1,      // (D,H)
    const float* __restrict__ b1,      // (H)
    const float* __restrict__ W2,      // (H,3K)
    const float* __restrict__ b2,      // (3K)
    float* __restrict__ ws_align)      // (B,T)
{
    const int b   = blockIdx.x;
    const int tid = threadIdx.x;

    __shared__ float hs[HH];
    __shared__ float pr[PP];

    // h[tid] = tanh(sum_d state[b,d] * W1[d,tid] + b1[tid])
    const float* st = state + (size_t)b * DD;
    float acc = b1[tid];
    #pragma unroll 8
    for (int d = 0; d < DD; ++d)
        acc += st[d] * W1[(size_t)d * HH + tid];
    hs[tid] = tanhf(acc);
    __syncthreads();

    // params[p] = exp(sum_i h[i] * W2[i,p] + b2[p])
    if (tid < PP) {
        float a = b2[tid];
        for (int i = 0; i < HH; ++i)
            a += hs[i] * W2[(size_t)i * PP + tid];
        pr[tid] = expf(a);
    }
    __syncthreads();

    float m[KK], inv_s[KK];
    #pragma unroll
    for (int k = 0; k < KK; ++k) {
        m[k]     = pr[3*k];
        inv_s[k] = 1.0f / pr[3*k + 1];
    }

    // align[b,t] = sum_k sigmoid((t+0.5-m)/s) - sigmoid((t-0.5-m)/s)
    for (int t = tid; t < TT; t += 256) {
        const float tf = (float)t;
        float al = 0.0f;
        #pragma unroll
        for (int k = 0; k < KK; ++k) {
            float hi = (tf + 0.5f - m[k]) * inv_s[k];
            float lo = (tf - 0.5f - m[k]) * inv_s[k];
            float sh = 1.0f / (1.0f + expf(-hi));
            float sl = 1.0f / (1.0f + expf(-lo));
            al += sh - sl;
        }
        ws_align[(size_t)b * TT + t] = al;
    }
}

// ---------------------------------------------------------------------------
// Kernel 2: partial context[b,chunk,d] = sum_{t in chunk} align[b,t]*enc_z[b,t,d]
// ---------------------------------------------------------------------------
__global__ __launch_bounds__(128) void reduce_partial_kernel(
    const float* __restrict__ enc_z,   // (B,T,D)
    const float* __restrict__ align,   // (B,T)
    float* __restrict__ partial)       // (B,TCHUNKS,D)
{
    const int b   = blockIdx.x;
    const int c   = blockIdx.y;
    const int tid = threadIdx.x;       // 0..127 -> float4 column

    __shared__ float al[TCHUNK];
    const int t0 = c * TCHUNK;
    if (tid < TCHUNK) al[tid] = align[(size_t)b * TT + t0 + tid];
    __syncthreads();

    const float4* e4 = (const float4*)enc_z + (size_t)(b * TT + t0) * D4 + tid;

    float4 acc = make_float4(0.f, 0.f, 0.f, 0.f);
    #pragma unroll 5
    for (int t = 0; t < TCHUNK; ++t) {
        const float a  = al[t];
        const float4 v = e4[(size_t)t * D4];
        acc.x += a * v.x;
        acc.y += a * v.y;
        acc.z += a * v.z;
        acc.w += a * v.w;
    }
    ((float4*)partial)[(size_t)(b * TCHUNKS + c) * D4 + tid] = acc;
}

// ---------------------------------------------------------------------------
// Kernel 3: context[b,d] = sum_c partial[b,c,d]
// ---------------------------------------------------------------------------
__global__ __launch_bounds__(128) void final_reduce_kernel(
    const float* __restrict__ partial, // (B,TCHUNKS,D)
    float* __restrict__ out)           // (B,1,D)
{
    const int b   = blockIdx.x;
    const int tid = threadIdx.x;       // 0..127

    const float4* p4 = (const float4*)partial + (size_t)b * TCHUNKS * D4 + tid;
    float4 acc = make_float4(0.f, 0.f, 0.f, 0.f);
    #pragma unroll
    for (int c = 0; c < TCHUNKS; ++c) {
        const float4 v = p4[(size_t)c * D4];
        acc.x += v.x; acc.y += v.y; acc.z += v.z; acc.w += v.w;
    }
    ((float4*)out)[(size_t)b * D4 + tid] = acc;
}

extern "C" void kernel_launch(void* const* d_in, const int* in_sizes, int n_in,
                              void* d_out, int out_size, void* d_ws, size_t ws_size,
                              hipStream_t stream) {
    const float* state = (const float*)d_in[0];
    const float* enc_z = (const float*)d_in[1];
    const float* W1    = (const float*)d_in[2];
    const float* b1    = (const float*)d_in[3];
    const float* W2    = (const float*)d_in[4];
    const float* b2    = (const float*)d_in[5];
    float* out = (float*)d_out;

    float* ws_align   = (float*)d_ws;                       // B*T floats
    float* ws_partial = ws_align + (size_t)BB * TT;         // B*TCHUNKS*D floats

    mlp_align_kernel<<<BB, 256, 0, stream>>>(state, W1, b1, W2, b2, ws_align);
    reduce_partial_kernel<<<dim3(BB, TCHUNKS), 128, 0, stream>>>(enc_z, ws_align, ws_partial);
    final_reduce_kernel<<<BB, 128, 0, stream>>>(ws_partial, out);
}

// Round 2
// 60.749 us; speedup vs baseline: 1.3414x; 1.3414x over previous
//
#include <hip/hip_runtime.h>
#include <math.h>

#define BB 64
#define TT 2000
#define DD 512
#define HH 256
#define KK 5
#define PP (3*KK)             // 15
#define TCHUNKS 40
#define TCHUNK (TT/TCHUNKS)   // 50
#define D4 (DD/4)             // 128

// ws layout (floats):
//   [0, BB*TT)                          align        (128000)
//   [BB*TT, BB*TT + BB*TCHUNKS*DD)      partials     (1310720)
// total ≈ 5.8 MB

// ---------------------------------------------------------------------------
// Kernel 1: per-batch MLP (state@W1 -> tanh -> @W2 -> exp) + align.
// softmax over singleton axis == 1, so weights drop out.
// ---------------------------------------------------------------------------
__global__ __launch_bounds__(256) void mlp_align_kernel(
    const float* __restrict__ state,   // (B,1,D)
    const float* __restrict__ W1,      // (D,H) row-major
    const float* __restrict__ b1,      // (H)
    const float* __restrict__ W2,      // (H,3K) row-major
    const float* __restrict__ b2,      // (3K)
    float* __restrict__ ws_align)      // (B,T)
{
    const int b    = blockIdx.x;
    const int tid  = threadIdx.x;
    const int wave = tid >> 6;          // 0..3
    const int lane = tid & 63;

    __shared__ float s_state[DD];
    __shared__ float s_part[4][HH];     // 4 wave-partials per output
    __shared__ float hs[HH];
    __shared__ float s_red[16][17];     // W2-stage reduction (pad vs conflicts)
    __shared__ float pr[PP];

    // stage state row in LDS (broadcast reads later are conflict-free)
    for (int d = tid; d < DD; d += 256) s_state[d] = state[(size_t)b * DD + d];
    __syncthreads();

    // h: wave w covers d in [128w,128w+128); lane owns outputs 4*lane..4*lane+3
    // W1[d][4*lane..4*lane+3] is float4 index d*64 + lane  (coalesced 16B/lane)
    {
        const int d0 = wave * 128;
        const float4* w1v = (const float4*)W1;
        float4 acc = make_float4(0.f, 0.f, 0.f, 0.f);
        #pragma unroll 16
        for (int dd = 0; dd < 128; ++dd) {
            const int d = d0 + dd;
            const float s  = s_state[d];
            const float4 w = w1v[(size_t)d * 64 + lane];
            acc.x += s * w.x; acc.y += s * w.y;
            acc.z += s * w.z; acc.w += s * w.w;
        }
        s_part[wave][4*lane+0] = acc.x;
        s_part[wave][4*lane+1] = acc.y;
        s_part[wave][4*lane+2] = acc.z;
        s_part[wave][4*lane+3] = acc.w;
    }
    __syncthreads();

    hs[tid] = tanhf(b1[tid] + s_part[0][tid] + s_part[1][tid]
                            + s_part[2][tid] + s_part[3][tid]);
    __syncthreads();

    // params: 16 groups of 16 threads; group p computes param p (p<15)
    {
        const int p = tid >> 4;         // 0..15
        const int g = tid & 15;         // 0..15
        float a = 0.f;
        if (p < PP) {
            #pragma unroll
            for (int i = 0; i < 16; ++i)
                a += hs[g + 16*i] * W2[(size_t)(g + 16*i) * PP + p];
        }
        s_red[p][g] = a;
    }
    __syncthreads();
    if (tid < PP) {
        float a = b2[tid];
        #pragma unroll
        for (int g = 0; g < 16; ++g) a += s_red[tid][g];
        pr[tid] = expf(a);
    }
    __syncthreads();

    float m[KK], inv_s[KK];
    #pragma unroll
    for (int k = 0; k < KK; ++k) {
        m[k]     = pr[3*k];
        inv_s[k] = 1.0f / pr[3*k + 1];
    }

    // align[b,t] = sum_k sigmoid((t+0.5-m)/s) - sigmoid((t-0.5-m)/s)
    for (int t = tid; t < TT; t += 256) {
        const float tf = (float)t;
        float al = 0.0f;
        #pragma unroll
        for (int k = 0; k < KK; ++k) {
            const float hi = (tf + 0.5f - m[k]) * inv_s[k];
            const float lo = (tf - 0.5f - m[k]) * inv_s[k];
            al += 1.0f / (1.0f + expf(-hi)) - 1.0f / (1.0f + expf(-lo));
        }
        ws_align[(size_t)b * TT + t] = al;
    }
}

// ---------------------------------------------------------------------------
// Kernel 2: partial[b,c,d] = sum_{t in chunk c} align[b,t] * enc_z[b,t,d]
// 2560 blocks (10/CU, 20 waves/CU) — streaming, HBM-bound.
// ---------------------------------------------------------------------------
__global__ __launch_bounds__(128) void reduce_partial_kernel(
    const float* __restrict__ enc_z,   // (B,T,D)
    const float* __restrict__ align,   // (B,T)
    float* __restrict__ partial)       // (B,TCHUNKS,D)
{
    const int b   = blockIdx.x;
    const int c   = blockIdx.y;
    const int tid = threadIdx.x;       // 0..127 -> float4 column

    __shared__ float al[TCHUNK];
    const int t0 = c * TCHUNK;
    if (tid < TCHUNK) al[tid] = align[(size_t)b * TT + t0 + tid];
    __syncthreads();

    const float4* e4 = (const float4*)enc_z + (size_t)(b * TT + t0) * D4 + tid;

    float4 acc = make_float4(0.f, 0.f, 0.f, 0.f);
    #pragma unroll 10
    for (int t = 0; t < TCHUNK; ++t) {
        const float a  = al[t];
        const float4 v = e4[(size_t)t * D4];
        acc.x += a * v.x;
        acc.y += a * v.y;
        acc.z += a * v.z;
        acc.w += a * v.w;
    }
    ((float4*)partial)[(size_t)(b * TCHUNKS + c) * D4 + tid] = acc;
}

// ---------------------------------------------------------------------------
// Kernel 3: context[b,d] = sum_c partial[b,c,d]
// ---------------------------------------------------------------------------
__global__ __launch_bounds__(128) void final_reduce_kernel(
    const float* __restrict__ partial, // (B,TCHUNKS,D)
    float* __restrict__ out)           // (B,1,D)
{
    const int b   = blockIdx.x;
    const int tid = threadIdx.x;       // 0..127

    const float4* p4 = (const float4*)partial + (size_t)b * TCHUNKS * D4 + tid;
    float4 acc = make_float4(0.f, 0.f, 0.f, 0.f);
    #pragma unroll
    for (int c = 0; c < TCHUNKS; ++c) {
        const float4 v = p4[(size_t)c * D4];
        acc.x += v.x; acc.y += v.y; acc.z += v.z; acc.w += v.w;
    }
    ((float4*)out)[(size_t)b * D4 + tid] = acc;
}

extern "C" void kernel_launch(void* const* d_in, const int* in_sizes, int n_in,
                              void* d_out, int out_size, void* d_ws, size_t ws_size,
                              hipStream_t stream) {
    const float* state = (const float*)d_in[0];
    const float* enc_z = (const float*)d_in[1];
    const float* W1    = (const float*)d_in[2];
    const float* b1    = (const float*)d_in[3];
    const float* W2    = (const float*)d_in[4];
    const float* b2    = (const float*)d_in[5];
    float* out = (float*)d_out;

    float* ws_align   = (float*)d_ws;                   // B*T floats
    float* ws_partial = ws_align + (size_t)BB * TT;     // B*TCHUNKS*D floats

    mlp_align_kernel<<<BB, 256, 0, stream>>>(state, W1, b1, W2, b2, ws_align);
    reduce_partial_kernel<<<dim3(BB, TCHUNKS), 128, 0, stream>>>(enc_z, ws_align, ws_partial);
    final_reduce_kernel<<<BB, 128, 0, stream>>>(ws_partial, out);
}